// Round 1
// baseline (669.581 us; speedup 1.0000x reference)
//
#include <hip/hip_runtime.h>
#include <math.h>

#define N_BINS 15

// One wave (64 lanes) per row. C=1000 -> 250 float4 loads per row, each lane
// holds up to 4 float4s (16 floats) in registers so the row is read from HBM
// exactly once (max pass + exp-sum pass both hit registers).
__global__ __launch_bounds__(256) void ecce_rows_kernel(
    const float* __restrict__ logits,
    const int* __restrict__ labels,
    float* __restrict__ seg_buf,   // C * N_BINS floats, pre-zeroed
    int N, int C)
{
    const int lane = threadIdx.x & 63;
    const int wave = threadIdx.x >> 6;
    const int row  = blockIdx.x * 4 + wave;
    if (row >= N) return;

    const int n4 = C >> 2;  // number of float4s per row (C assumed %4==0)
    const float4* __restrict__ rowp =
        (const float4*)(logits + (size_t)row * (size_t)C);

    float v[16];
    #pragma unroll
    for (int k = 0; k < 4; ++k) {
        const int j = lane + 64 * k;
        if (j < n4) {
            float4 f = rowp[j];
            v[4*k+0] = f.x; v[4*k+1] = f.y; v[4*k+2] = f.z; v[4*k+3] = f.w;
        } else {
            v[4*k+0] = v[4*k+1] = v[4*k+2] = v[4*k+3] = -INFINITY;
        }
    }

    // Lane-local max + argmax (ascending element index per lane -> first-occurrence)
    float m = -INFINITY;
    int am = 0x7fffffff;
    #pragma unroll
    for (int k = 0; k < 16; ++k) {
        const int idx = 4 * (lane + 64 * (k >> 2)) + (k & 3);
        if (v[k] > m) { m = v[k]; am = idx; }
    }

    // Wave butterfly reduce: (max value, min index on tie)
    #pragma unroll
    for (int off = 32; off >= 1; off >>= 1) {
        const float om = __shfl_xor(m, off, 64);
        const int   oi = __shfl_xor(am, off, 64);
        if (om > m || (om == m && oi < am)) { m = om; am = oi; }
    }

    // Sum exp(x - max); filler slots are -INF -> exp -> 0
    float s = 0.0f;
    #pragma unroll
    for (int k = 0; k < 16; ++k) s += __expf(v[k] - m);

    #pragma unroll
    for (int off = 32; off >= 1; off >>= 1) s += __shfl_xor(s, off, 64);

    if (lane == 0) {
        const float conf = 1.0f / s;               // exp(m-m)/sum = 1/s
        int bin = (int)ceilf(conf * (float)N_BINS) - 1;
        bin = bin < 0 ? 0 : (bin > N_BINS - 1 ? N_BINS - 1 : bin);
        const int label = labels[row];
        const float acc = (am == label) ? 1.0f : 0.0f;
        atomicAdd(&seg_buf[label * N_BINS + bin], conf - acc);
    }
}

// Single-block final reduction: ecce = sum(|seg_buf[i]|) / N
__global__ __launch_bounds__(256) void ecce_final_kernel(
    const float* __restrict__ seg_buf, float* __restrict__ out,
    int nseg, float invN)
{
    __shared__ float sdata[4];
    float s = 0.0f;
    for (int i = threadIdx.x; i < nseg; i += 256) s += fabsf(seg_buf[i]);
    #pragma unroll
    for (int off = 32; off >= 1; off >>= 1) s += __shfl_xor(s, off, 64);
    const int lane = threadIdx.x & 63;
    const int wave = threadIdx.x >> 6;
    if (lane == 0) sdata[wave] = s;
    __syncthreads();
    if (threadIdx.x == 0)
        out[0] = (sdata[0] + sdata[1] + sdata[2] + sdata[3]) * invN;
}

extern "C" void kernel_launch(void* const* d_in, const int* in_sizes, int n_in,
                              void* d_out, int out_size, void* d_ws, size_t ws_size,
                              hipStream_t stream) {
    const float* logits = (const float*)d_in[0];
    const int*   labels = (const int*)d_in[1];
    const int N = in_sizes[1];
    const int C = in_sizes[0] / N;
    const int nseg = C * N_BINS;

    float* seg_buf = (float*)d_ws;
    hipMemsetAsync(seg_buf, 0, (size_t)nseg * sizeof(float), stream);

    const int rows_per_block = 4;  // 4 waves x 64 lanes
    dim3 grid((N + rows_per_block - 1) / rows_per_block);
    ecce_rows_kernel<<<grid, 256, 0, stream>>>(logits, labels, seg_buf, N, C);

    ecce_final_kernel<<<1, 256, 0, stream>>>(seg_buf, (float*)d_out, nseg, 1.0f / (float)N);
}

// Round 3
// 639.604 us; speedup vs baseline: 1.0469x; 1.0469x over previous
//
#include <hip/hip_runtime.h>
#include <math.h>

#define N_BINS 15

typedef float vfloat4 __attribute__((ext_vector_type(4)));

// One wave (64 lanes) per row; C=1000 -> 250 float4s, 4 per lane (clamped).
// Row read from HBM exactly once (nontemporal), both passes hit registers.
__global__ __launch_bounds__(256) void ecce_rows_kernel(
    const float* __restrict__ logits,
    const int* __restrict__ labels,
    float* __restrict__ seg_buf,   // C * N_BINS floats, pre-zeroed
    int N, int C)
{
    const int lane = threadIdx.x & 63;
    const int wv   = threadIdx.x >> 6;
    const int row  = blockIdx.x * 4 + wv;
    if (row >= N) return;

    const int n4 = C >> 2;  // float4s per row (C % 4 == 0)
    const vfloat4* __restrict__ rowp =
        (const vfloat4*)(logits + (size_t)row * (size_t)C);

    // Unconditional clamped loads: out-of-range lanes re-read the last float4
    // (same cacheline, no exec-mask divergence), then get overwritten by -INF.
    float v[16];
    bool valid[4];
    #pragma unroll
    for (int g = 0; g < 4; ++g) {
        const int j = lane + 64 * g;
        valid[g] = (j < n4);
        const int jc = valid[g] ? j : (n4 - 1);
        const vfloat4 f = __builtin_nontemporal_load(&rowp[jc]);
        v[4*g+0] = f.x; v[4*g+1] = f.y; v[4*g+2] = f.z; v[4*g+3] = f.w;
    }
    #pragma unroll
    for (int g = 0; g < 4; ++g)
        if (!valid[g]) { v[4*g+0] = v[4*g+1] = v[4*g+2] = v[4*g+3] = -INFINITY; }

    // Wave max: lane-local tree + 6-round butterfly (max only, no index carry)
    float m = v[0];
    #pragma unroll
    for (int k = 1; k < 16; ++k) m = fmaxf(m, v[k]);
    #pragma unroll
    for (int off = 32; off >= 1; off >>= 1)
        m = fmaxf(m, __shfl_xor(m, off, 64));

    // First-occurrence argmax: min true-element-index among v==m, 6-round min
    int cand = 0x7fffffff;
    #pragma unroll
    for (int g = 0; g < 4; ++g) {
        #pragma unroll
        for (int e = 0; e < 4; ++e) {
            const int idx = 4 * (lane + 64 * g) + e;
            if (v[4*g+e] == m && idx < cand) cand = idx;
        }
    }
    #pragma unroll
    for (int off = 32; off >= 1; off >>= 1) {
        const int oc = __shfl_xor(cand, off, 64);
        cand = oc < cand ? oc : cand;
    }

    // Softmax denominator: sum exp(x - m); -INF fillers contribute 0
    float s = 0.0f;
    #pragma unroll
    for (int k = 0; k < 16; ++k) s += __expf(v[k] - m);
    #pragma unroll
    for (int off = 32; off >= 1; off >>= 1)
        s += __shfl_xor(s, off, 64);

    if (lane == 0) {
        const float conf = 1.0f / s;               // exp(m-m)/sum
        int bin = (int)ceilf(conf * (float)N_BINS) - 1;
        bin = bin < 0 ? 0 : (bin > N_BINS - 1 ? N_BINS - 1 : bin);
        const int label = labels[row];
        const float acc = (cand == label) ? 1.0f : 0.0f;
        atomicAdd(&seg_buf[label * N_BINS + bin], conf - acc);
    }
}

// Single-block final reduction: ecce = sum(|seg_buf[i]|) / N
__global__ __launch_bounds__(256) void ecce_final_kernel(
    const float* __restrict__ seg_buf, float* __restrict__ out,
    int nseg, float invN)
{
    __shared__ float sdata[4];
    float s = 0.0f;
    for (int i = threadIdx.x; i < nseg; i += 256) s += fabsf(seg_buf[i]);
    #pragma unroll
    for (int off = 32; off >= 1; off >>= 1) s += __shfl_xor(s, off, 64);
    const int lane = threadIdx.x & 63;
    const int wv   = threadIdx.x >> 6;
    if (lane == 0) sdata[wv] = s;
    __syncthreads();
    if (threadIdx.x == 0)
        out[0] = (sdata[0] + sdata[1] + sdata[2] + sdata[3]) * invN;
}

extern "C" void kernel_launch(void* const* d_in, const int* in_sizes, int n_in,
                              void* d_out, int out_size, void* d_ws, size_t ws_size,
                              hipStream_t stream) {
    const float* logits = (const float*)d_in[0];
    const int*   labels = (const int*)d_in[1];
    const int N = in_sizes[1];
    const int C = in_sizes[0] / N;
    const int nseg = C * N_BINS;

    float* seg_buf = (float*)d_ws;
    (void)hipMemsetAsync(seg_buf, 0, (size_t)nseg * sizeof(float), stream);

    const int rows_per_block = 4;  // 4 waves x 64 lanes
    dim3 grid((N + rows_per_block - 1) / rows_per_block);
    ecce_rows_kernel<<<grid, 256, 0, stream>>>(logits, labels, seg_buf, N, C);

    ecce_final_kernel<<<1, 256, 0, stream>>>(seg_buf, (float*)d_out, nseg, 1.0f / (float)N);
}